// Round 10
// baseline (523.697 us; speedup 1.0000x reference)
//
#include <hip/hip_runtime.h>

#define LOG2E 1.44269504088896340736f
#define LN2   0.69314718055994530942f

typedef __attribute__((ext_vector_type(8))) short bf16x8;
typedef __attribute__((ext_vector_type(4))) float f32x4;
typedef __attribute__((ext_vector_type(16))) float f32x16;

// ws float offsets
#define WS_MUP  0        // 8192 x 16 u32 : packed [mu_hi|mu_lo] bf16
#define WS_SPT  131072   // 8192 x 16 u32 : packed [sp'_hi|sp'_lo]
#define WS_AV1  262144   // 8192 f32
#define WS_P1   270336   // 64 x 8192 f32
#define WS_P2   794624   // 64 x 8192 f32
#define WS_BAR  1318912  // 2 ints: arrive counter, generation

#define NBLK 1024

__device__ __forceinline__ unsigned short bf16_rne(float x) {
  unsigned int u = __float_as_uint(x);
  u = u + 0x7FFFu + ((u >> 16) & 1u);
  return (unsigned short)(u >> 16);
}
__device__ __forceinline__ float bf16f(unsigned short h) {
  return __uint_as_float(((unsigned int)h) << 16);
}
__device__ __forceinline__ float fast_exp2(float x) {
#if __has_builtin(__builtin_amdgcn_exp2f)
  return __builtin_amdgcn_exp2f(x);
#else
  return exp2f(x);
#endif
}
__device__ __forceinline__ float fast_log2(float x) {
#if __has_builtin(__builtin_amdgcn_logf)
  return __builtin_amdgcn_logf(x);
#else
  return log2f(x);
#endif
}

// Sense-reversing grid barrier. Safe: grid == 1024 == 4 blocks/CU x 256 CU,
// co-residency forced by __launch_bounds__(256,4) (VGPR<=128, LDS 11.8KB).
__device__ __forceinline__ void grid_sync(int* bar, int* gen) {
  __syncthreads();
  if (threadIdx.x == 0) {
    __threadfence();
    int g = __hip_atomic_load(gen, __ATOMIC_ACQUIRE, __HIP_MEMORY_SCOPE_AGENT);
    int a = __hip_atomic_fetch_add(bar, 1, __ATOMIC_ACQ_REL, __HIP_MEMORY_SCOPE_AGENT);
    if (a == NBLK - 1) {
      __hip_atomic_store(bar, 0, __ATOMIC_RELAXED, __HIP_MEMORY_SCOPE_AGENT);
      __hip_atomic_store(gen, g + 1, __ATOMIC_RELEASE, __HIP_MEMORY_SCOPE_AGENT);
    } else {
      while (__hip_atomic_load(gen, __ATOMIC_ACQUIRE, __HIP_MEMORY_SCOPE_AGENT) == g) {
        __builtin_amdgcn_s_sleep(2);
      }
    }
    __threadfence();
  }
  __syncthreads();
}

__device__ __forceinline__ void pack_row(const float* v, unsigned int* buf) {
#pragma unroll
  for (int k = 0; k < 16; k += 2) {
    unsigned short h0 = bf16_rne(v[k]);
    unsigned short h1 = bf16_rne(v[k + 1]);
    float l0 = v[k] - bf16f(h0);
    float l1 = v[k + 1] - bf16f(h1);
    buf[k >> 1] = (unsigned int)h0 | ((unsigned int)h1 << 16);
    buf[8 + (k >> 1)] = (unsigned int)bf16_rne(l0) | ((unsigned int)bf16_rne(l1) << 16);
  }
}

#define EXPSUM16(d, acc)                                              \
  {                                                                   \
    float e0 = fast_exp2(d[0])  + fast_exp2(d[1]);                    \
    float e1 = fast_exp2(d[2])  + fast_exp2(d[3]);                    \
    float e2 = fast_exp2(d[4])  + fast_exp2(d[5]);                    \
    float e3 = fast_exp2(d[6])  + fast_exp2(d[7]);                    \
    float e4 = fast_exp2(d[8])  + fast_exp2(d[9]);                    \
    float e5 = fast_exp2(d[10]) + fast_exp2(d[11]);                   \
    float e6 = fast_exp2(d[12]) + fast_exp2(d[13]);                   \
    float e7 = fast_exp2(d[14]) + fast_exp2(d[15]);                   \
    acc += ((e0 + e1) + (e2 + e3)) + ((e4 + e5) + (e6 + e7));         \
  }

// One pass-chunk: part[chunk][r0..] += exp2 sums; two stationary strips/wave.
__device__ __forceinline__ void inner_pass(
    const unsigned int* __restrict__ statv, float* __restrict__ part,
    int chunk, int sg, int t,
    const unsigned int* __restrict__ tl, const float* __restrict__ av_l) {
  const int l = t & 63;
  const int wave = t >> 6;
  const int lr = l & 31;
  const int hi = l >> 5;
  const int r0 = sg * 256 + wave * 64;

  const unsigned int* brow0 = statv + (size_t)(r0 + lr) * 16 + hi * 4;
  const unsigned int* brow1 = statv + (size_t)(r0 + 32 + lr) * 16 + hi * 4;
  const bf16x8 b_hi0 = *(const bf16x8*)brow0;
  const bf16x8 b_lo0 = *(const bf16x8*)(brow0 + 8);
  const bf16x8 b_hi1 = *(const bf16x8*)brow1;
  const bf16x8 b_lo1 = *(const bf16x8*)(brow1 + 8);

  float acc0 = 0.f, acc1 = 0.f;
#pragma unroll
  for (int tile = 0; tile < 4; ++tile) {
    const unsigned int* arow = tl + (tile * 32 + lr) * 20 + hi * 4;
    const bf16x8 a_hi = *(const bf16x8*)arow;
    const bf16x8 a_lo = *(const bf16x8*)(arow + 8);

    const f32x4 c0 = *(const f32x4*)(av_l + tile * 32 + 0  + 4 * hi);
    const f32x4 c1 = *(const f32x4*)(av_l + tile * 32 + 8  + 4 * hi);
    const f32x4 c2 = *(const f32x4*)(av_l + tile * 32 + 16 + 4 * hi);
    const f32x4 c3 = *(const f32x4*)(av_l + tile * 32 + 24 + 4 * hi);
    f32x16 d0, d1;
#pragma unroll
    for (int e = 0; e < 4; ++e) {
      d0[e] = c0[e]; d0[4 + e] = c1[e]; d0[8 + e] = c2[e]; d0[12 + e] = c3[e];
      d1[e] = c0[e]; d1[4 + e] = c1[e]; d1[8 + e] = c2[e]; d1[12 + e] = c3[e];
    }
    d0 = __builtin_amdgcn_mfma_f32_32x32x16_bf16(a_hi, b_hi0, d0, 0, 0, 0);
    d0 = __builtin_amdgcn_mfma_f32_32x32x16_bf16(a_lo, b_hi0, d0, 0, 0, 0);
    d0 = __builtin_amdgcn_mfma_f32_32x32x16_bf16(a_hi, b_lo0, d0, 0, 0, 0);
    d1 = __builtin_amdgcn_mfma_f32_32x32x16_bf16(a_hi, b_hi1, d1, 0, 0, 0);
    d1 = __builtin_amdgcn_mfma_f32_32x32x16_bf16(a_lo, b_hi1, d1, 0, 0, 0);
    d1 = __builtin_amdgcn_mfma_f32_32x32x16_bf16(a_hi, b_lo1, d1, 0, 0, 0);

    EXPSUM16(d0, acc0)
    EXPSUM16(d1, acc1)
  }
  acc0 += __shfl_xor(acc0, 32);
  acc1 += __shfl_xor(acc1, 32);
  if (l < 32) part[(size_t)chunk * 8192 + r0 + lr] = acc0;
  else        part[(size_t)chunk * 8192 + r0 + 32 + lr] = acc1;
}

__global__ __launch_bounds__(256, 4) void k_fused(
    const float* __restrict__ particles, const float* __restrict__ lw,
    const float* __restrict__ sp, const float* __restrict__ w,
    const float* __restrict__ A, const float* __restrict__ Bm,
    unsigned int* __restrict__ muP, unsigned int* __restrict__ spT,
    float* __restrict__ av1, float* __restrict__ p1, float* __restrict__ p2,
    float* __restrict__ out, int* __restrict__ bar, int* __restrict__ gen) {
  __shared__ __align__(16) unsigned int tl[128 * 20];
  __shared__ __align__(16) float av_l[128];
  __shared__ float sums[256];
  const int t = threadIdx.x;
  const int bx = blockIdx.x;  // 0..63 : chunk
  const int by = blockIdx.y;  // 0..15
  const int bid = by * 64 + bx;

  // ---- P0: prep. 8 rows per block (threads 0..7, one full row each). ----
  if (t < 8) {
    const int j = bid * 8 + t;
    float x[24];
    {
      const float4* p4 = (const float4*)(particles + (size_t)j * 24);
#pragma unroll
      for (int q = 0; q < 6; ++q) {
        float4 v = p4[q];
        x[q * 4 + 0] = v.x; x[q * 4 + 1] = v.y; x[q * 4 + 2] = v.z; x[q * 4 + 3] = v.w;
      }
    }
    float mrow[16];
    float m2 = 0.f;
#pragma unroll
    for (int k = 0; k < 16; ++k) {
      float s = 0.f;
#pragma unroll
      for (int l2 = 0; l2 < 16; ++l2) s += x[l2] * A[k * 16 + l2];
#pragma unroll
      for (int l2 = 0; l2 < 8; ++l2) s += x[16 + l2] * Bm[k * 8 + l2];
      mrow[k] = s;
      m2 += s * s;
    }
    av1[j] = LOG2E * (lw[j] - 0.5f * m2);

    unsigned int buf[16];
    pack_row(mrow, buf);
    {
      uint4* dst = (uint4*)(muP + (size_t)j * 16);
#pragma unroll
      for (int q = 0; q < 4; ++q)
        dst[q] = make_uint4(buf[q * 4], buf[q * 4 + 1], buf[q * 4 + 2], buf[q * 4 + 3]);
    }
    float srow[16];
    {
      const float4* s4 = (const float4*)(sp + (size_t)j * 16);
#pragma unroll
      for (int q = 0; q < 4; ++q) {
        float4 v = s4[q];
        srow[q * 4 + 0] = LOG2E * v.x; srow[q * 4 + 1] = LOG2E * v.y;
        srow[q * 4 + 2] = LOG2E * v.z; srow[q * 4 + 3] = LOG2E * v.w;
      }
    }
    pack_row(srow, buf);
    {
      uint4* dst = (uint4*)(spT + (size_t)j * 16);
#pragma unroll
      for (int q = 0; q < 4; ++q)
        dst[q] = make_uint4(buf[q * 4], buf[q * 4 + 1], buf[q * 4 + 2], buf[q * 4 + 3]);
    }
  }
  grid_sync(bar, gen);

  // ---- P1: pass 1. tile = mu chunk bx (av1); stationary = sp'. ----
  {
    const uint4* src = (const uint4*)(muP + (size_t)bx * 2048);
#pragma unroll
    for (int q = 0; q < 2; ++q) {
      int f = t + 256 * q;
      int row = f >> 2, s = f & 3;
      *(uint4*)(tl + row * 20 + s * 4) = src[f];
    }
    if (t < 128) av_l[t] = av1[bx * 128 + t];
  }
  __syncthreads();
  inner_pass(spT, p1, bx, by, t, tl, av_l);
  inner_pass(spT, p1, bx, by + 16, t, tl, av_l);
  grid_sync(bar, gen);

  // ---- P2: pass 2. tile = sp' chunk bx (av2 from p1); stationary = mu. ----
  {
    const uint4* src = (const uint4*)(spT + (size_t)bx * 2048);
#pragma unroll
    for (int q = 0; q < 2; ++q) {
      int f = t + 256 * q;
      int row = f >> 2, s = f & 3;
      *(uint4*)(tl + row * 20 + s * 4) = src[f];
    }
    const int row = t & 127, half = t >> 7;
    float s = 0.f;
    const float* p = p1 + (size_t)(half * 32) * 8192 + bx * 128 + row;
#pragma unroll 8
    for (int c = 0; c < 32; ++c) s += p[(size_t)c * 8192];
    sums[t] = s;
    __syncthreads();
    if (t < 128) {
      float sv = sums[t] + sums[t + 128];
      av_l[t] = LOG2E * w[bx * 128 + t] - fast_log2(sv);
    }
  }
  __syncthreads();
  inner_pass(muP, p2, bx, by, t, tl, av_l);
  inner_pass(muP, p2, bx, by + 16, t, tl, av_l);
  grid_sync(bar, gen);

  // ---- P3: output. 8 rows per block; 32 lanes per row sum 64 partials. ----
  {
    const int j = bid * 8 + (t >> 5);
    const int c = t & 31;
    float s = p2[(size_t)c * 8192 + j] + p2[(size_t)(c + 32) * 8192 + j];
    s += __shfl_xor(s, 1);
    s += __shfl_xor(s, 2);
    s += __shfl_xor(s, 4);
    s += __shfl_xor(s, 8);
    s += __shfl_xor(s, 16);
    if (c == 0) out[j] = LN2 * (av1[j] + fast_log2(s));
  }
}

extern "C" void kernel_launch(void* const* d_in, const int* in_sizes, int n_in,
                              void* d_out, int out_size, void* d_ws, size_t ws_size,
                              hipStream_t stream) {
  const float* particles = (const float*)d_in[0];
  const float* lw        = (const float*)d_in[1];
  const float* sp        = (const float*)d_in[2];
  const float* w         = (const float*)d_in[3];
  const float* A         = (const float*)d_in[4];
  const float* Bm        = (const float*)d_in[5];

  float* ws = (float*)d_ws;
  unsigned int* muP = (unsigned int*)(ws + WS_MUP);
  unsigned int* spT = (unsigned int*)(ws + WS_SPT);
  float* av1 = ws + WS_AV1;
  float* p1  = ws + WS_P1;
  float* p2  = ws + WS_P2;
  int* bar   = (int*)(ws + WS_BAR);
  int* gen   = bar + 1;
  float* out = (float*)d_out;

  hipMemsetAsync((void*)bar, 0, 2 * sizeof(int), stream);
  k_fused<<<dim3(64, 16), dim3(256), 0, stream>>>(
      particles, lw, sp, w, A, Bm, muP, spT, av1, p1, p2, out, bar, gen);
}

// Round 11
// 63.113 us; speedup vs baseline: 8.2977x; 8.2977x over previous
//
#include <hip/hip_runtime.h>

#define LOG2E 1.44269504088896340736f
#define LN2   0.69314718055994530942f

typedef __attribute__((ext_vector_type(8))) short bf16x8;
typedef __attribute__((ext_vector_type(4))) float f32x4;
typedef __attribute__((ext_vector_type(16))) float f32x16;

// ws float offsets
#define WS_MUP  0        // 8192 x 16 u32 : packed [mu_hi|mu_lo] bf16
#define WS_SPT  131072   // 8192 x 16 u32 : packed [sp'_hi|sp'_lo], sp' = log2e*sp
#define WS_AV1  262144   // 8192 f32
#define WS_P1   270336   // 64 x 8192 f32 partials, pass 1
#define WS_P2   794624   // 64 x 8192 f32 partials, pass 2

__device__ __forceinline__ unsigned short bf16_rne(float x) {
  unsigned int u = __float_as_uint(x);
  u = u + 0x7FFFu + ((u >> 16) & 1u);
  return (unsigned short)(u >> 16);
}
__device__ __forceinline__ float bf16f(unsigned short h) {
  return __uint_as_float(((unsigned int)h) << 16);
}
__device__ __forceinline__ float fast_exp2(float x) {
#if __has_builtin(__builtin_amdgcn_exp2f)
  return __builtin_amdgcn_exp2f(x);
#else
  return exp2f(x);
#endif
}
__device__ __forceinline__ float fast_log2(float x) {
#if __has_builtin(__builtin_amdgcn_logf)
  return __builtin_amdgcn_logf(x);
#else
  return log2f(x);
#endif
}

__device__ __forceinline__ void pack_row(const float* v, unsigned int* buf) {
#pragma unroll
  for (int k = 0; k < 16; k += 2) {
    unsigned short h0 = bf16_rne(v[k]);
    unsigned short h1 = bf16_rne(v[k + 1]);
    float l0 = v[k] - bf16f(h0);
    float l1 = v[k + 1] - bf16f(h1);
    buf[k >> 1] = (unsigned int)h0 | ((unsigned int)h1 << 16);
    buf[8 + (k >> 1)] = (unsigned int)bf16_rne(l0) | ((unsigned int)bf16_rne(l1) << 16);
  }
}

__global__ __launch_bounds__(256) void k_prep(
    const float* __restrict__ particles, const float* __restrict__ lw,
    const float* __restrict__ sp,
    const float* __restrict__ A, const float* __restrict__ B,
    unsigned int* __restrict__ muP, unsigned int* __restrict__ spT,
    float* __restrict__ av1) {
  int j = blockIdx.x * 256 + threadIdx.x;
  float x[24];
  {
    const float4* p4 = (const float4*)(particles + (size_t)j * 24);
#pragma unroll
    for (int q = 0; q < 6; ++q) {
      float4 v = p4[q];
      x[q * 4 + 0] = v.x; x[q * 4 + 1] = v.y; x[q * 4 + 2] = v.z; x[q * 4 + 3] = v.w;
    }
  }
  float mrow[16];
  float m2 = 0.f;
#pragma unroll
  for (int k = 0; k < 16; ++k) {
    float s = 0.f;
#pragma unroll
    for (int l = 0; l < 16; ++l) s += x[l] * A[k * 16 + l];
#pragma unroll
    for (int l = 0; l < 8; ++l) s += x[16 + l] * B[k * 8 + l];
    mrow[k] = s;
    m2 += s * s;
  }
  av1[j] = LOG2E * (lw[j] - 0.5f * m2);

  unsigned int buf[16];
  pack_row(mrow, buf);
  {
    uint4* dst = (uint4*)(muP + (size_t)j * 16);
#pragma unroll
    for (int q = 0; q < 4; ++q)
      dst[q] = make_uint4(buf[q * 4], buf[q * 4 + 1], buf[q * 4 + 2], buf[q * 4 + 3]);
  }
  float srow[16];
  {
    const float4* s4 = (const float4*)(sp + (size_t)j * 16);
#pragma unroll
    for (int q = 0; q < 4; ++q) {
      float4 v = s4[q];
      srow[q * 4 + 0] = LOG2E * v.x; srow[q * 4 + 1] = LOG2E * v.y;
      srow[q * 4 + 2] = LOG2E * v.z; srow[q * 4 + 3] = LOG2E * v.w;
    }
  }
  pack_row(srow, buf);
  {
    uint4* dst = (uint4*)(spT + (size_t)j * 16);
#pragma unroll
    for (int q = 0; q < 4; ++q)
      dst[q] = make_uint4(buf[q * 4], buf[q * 4 + 1], buf[q * 4 + 2], buf[q * 4 + 3]);
  }
}

// weighted exp-sum: acc += sum_e wq[e] * 2^(d[4q+e])
#define EXPSUM16W(d, c0, c1, c2, c3, acc)                               \
  {                                                                     \
    float m0 = c0[0] * fast_exp2(d[0])  + c0[1] * fast_exp2(d[1]);      \
    float m1 = c0[2] * fast_exp2(d[2])  + c0[3] * fast_exp2(d[3]);      \
    float m2 = c1[0] * fast_exp2(d[4])  + c1[1] * fast_exp2(d[5]);      \
    float m3 = c1[2] * fast_exp2(d[6])  + c1[3] * fast_exp2(d[7]);      \
    float m4 = c2[0] * fast_exp2(d[8])  + c2[1] * fast_exp2(d[9]);      \
    float m5 = c2[2] * fast_exp2(d[10]) + c2[3] * fast_exp2(d[11]);     \
    float m6 = c3[0] * fast_exp2(d[12]) + c3[1] * fast_exp2(d[13]);     \
    float m7 = c3[2] * fast_exp2(d[14]) + c3[3] * fast_exp2(d[15]);     \
    acc += ((m0 + m1) + (m2 + m3)) + ((m4 + m5) + (m6 + m7));           \
  }

// One sg-iteration: part[chunk][r0..] = weighted exp2 sums, 2 strips/wave.
// d chains from a persistent zero C-fragment (no per-tile accumulator init);
// eav_l holds 2^av per tile row, applied as weights in the exp-sum.
__device__ __forceinline__ void inner_pass(
    const unsigned int* __restrict__ statv, float* __restrict__ part,
    int chunk, int sg, int t,
    const unsigned int* __restrict__ tl, const float* __restrict__ eav_l,
    const f32x16 zc) {
  const int l = t & 63;
  const int wave = t >> 6;
  const int lr = l & 31;
  const int hi = l >> 5;
  const int r0 = sg * 256 + wave * 64;

  const unsigned int* brow0 = statv + (size_t)(r0 + lr) * 16 + hi * 4;
  const unsigned int* brow1 = statv + (size_t)(r0 + 32 + lr) * 16 + hi * 4;
  const bf16x8 b_hi0 = *(const bf16x8*)brow0;
  const bf16x8 b_lo0 = *(const bf16x8*)(brow0 + 8);
  const bf16x8 b_hi1 = *(const bf16x8*)brow1;
  const bf16x8 b_lo1 = *(const bf16x8*)(brow1 + 8);

  float acc0 = 0.f, acc1 = 0.f;
#pragma unroll
  for (int tile = 0; tile < 4; ++tile) {
    const unsigned int* arow = tl + (tile * 32 + lr) * 20 + hi * 4;
    const bf16x8 a_hi = *(const bf16x8*)arow;
    const bf16x8 a_lo = *(const bf16x8*)(arow + 8);

    // weights: eav[tile row], row = (reg&3) + 8*(reg>>2) + 4*hi
    const f32x4 c0 = *(const f32x4*)(eav_l + tile * 32 + 0  + 4 * hi);
    const f32x4 c1 = *(const f32x4*)(eav_l + tile * 32 + 8  + 4 * hi);
    const f32x4 c2 = *(const f32x4*)(eav_l + tile * 32 + 16 + 4 * hi);
    const f32x4 c3 = *(const f32x4*)(eav_l + tile * 32 + 24 + 4 * hi);

    f32x16 d0 = __builtin_amdgcn_mfma_f32_32x32x16_bf16(a_hi, b_hi0, zc, 0, 0, 0);
    d0 = __builtin_amdgcn_mfma_f32_32x32x16_bf16(a_lo, b_hi0, d0, 0, 0, 0);
    d0 = __builtin_amdgcn_mfma_f32_32x32x16_bf16(a_hi, b_lo0, d0, 0, 0, 0);
    f32x16 d1 = __builtin_amdgcn_mfma_f32_32x32x16_bf16(a_hi, b_hi1, zc, 0, 0, 0);
    d1 = __builtin_amdgcn_mfma_f32_32x32x16_bf16(a_lo, b_hi1, d1, 0, 0, 0);
    d1 = __builtin_amdgcn_mfma_f32_32x32x16_bf16(a_hi, b_lo1, d1, 0, 0, 0);

    EXPSUM16W(d0, c0, c1, c2, c3, acc0)
    EXPSUM16W(d1, c0, c1, c2, c3, acc1)
  }
  acc0 += __shfl_xor(acc0, 32);
  acc1 += __shfl_xor(acc1, 32);
  if (l < 32) part[(size_t)chunk * 8192 + r0 + lr] = acc0;
  else        part[(size_t)chunk * 8192 + r0 + 32 + lr] = acc1;
}

// part[chunk][r] = sum over 128 tile rows t of chunk of 2^( av[t] + stat_r . tile_t )
// Grid (64 chunks, 16 sg-groups); each block stages its tile once and runs TWO
// sg-iterations (sg = by and by+16). 1024 blocks = exactly 4/CU at (256,4).
__global__ __launch_bounds__(256, 4) void k_pass(
    const unsigned int* __restrict__ tilev,
    const unsigned int* __restrict__ statv,
    const float* __restrict__ avv,
    const float* __restrict__ psrc,
    float* __restrict__ part) {
  __shared__ __align__(16) unsigned int tl[128 * 20];
  __shared__ __align__(16) float eav_l[128];
  __shared__ float sums[256];
  const int t = threadIdx.x;
  const int chunk = blockIdx.x;  // 0..63, fast
  const int by    = blockIdx.y;  // 0..15

  // stage tile: 128 rows x 16 u32 -> LDS stride 20 (balanced b128 slots)
  {
    const uint4* src = (const uint4*)(tilev + (size_t)chunk * 2048);
#pragma unroll
    for (int q = 0; q < 2; ++q) {
      int f = t + 256 * q;
      int row = f >> 2, s = f & 3;
      *(uint4*)(tl + row * 20 + s * 4) = src[f];
    }
  }

  if (psrc == nullptr) {
    if (t < 128) eav_l[t] = fast_exp2(avv[chunk * 128 + t]);
  } else {
    const int row = t & 127, half = t >> 7;
    float s = 0.f;
    const float* p = psrc + (size_t)(half * 32) * 8192 + chunk * 128 + row;
#pragma unroll 8
    for (int c = 0; c < 32; ++c) s += p[(size_t)c * 8192];
    sums[t] = s;
    __syncthreads();
    if (t < 128) {
      float sv = sums[t] + sums[t + 128];
      // eav = 2^(log2e*w - log2(S1)) = 2^(log2e*w) / S1
      eav_l[t] = fast_exp2(LOG2E * avv[chunk * 128 + t]) / sv;
    }
  }
  __syncthreads();

  const f32x16 zc = {0.f, 0.f, 0.f, 0.f, 0.f, 0.f, 0.f, 0.f,
                     0.f, 0.f, 0.f, 0.f, 0.f, 0.f, 0.f, 0.f};
  inner_pass(statv, part, chunk, by, t, tl, eav_l, zc);
  inner_pass(statv, part, chunk, by + 16, t, tl, eav_l, zc);
}

__global__ __launch_bounds__(256) void k_out(
    const float* __restrict__ part, const float* __restrict__ av1,
    float* __restrict__ out) {
  int j = blockIdx.x * 256 + threadIdx.x;
  float s = 0.f;
#pragma unroll
  for (int c = 0; c < 64; ++c) s += part[(size_t)c * 8192 + j];
  out[j] = LN2 * (av1[j] + fast_log2(s));
}

extern "C" void kernel_launch(void* const* d_in, const int* in_sizes, int n_in,
                              void* d_out, int out_size, void* d_ws, size_t ws_size,
                              hipStream_t stream) {
  const float* particles = (const float*)d_in[0];
  const float* lw        = (const float*)d_in[1];
  const float* sp        = (const float*)d_in[2];
  const float* w         = (const float*)d_in[3];
  const float* A         = (const float*)d_in[4];
  const float* B         = (const float*)d_in[5];

  float* ws = (float*)d_ws;
  unsigned int* muP = (unsigned int*)(ws + WS_MUP);
  unsigned int* spT = (unsigned int*)(ws + WS_SPT);
  float* av1  = ws + WS_AV1;
  float* p1   = ws + WS_P1;
  float* p2   = ws + WS_P2;
  float* out  = (float*)d_out;

  k_prep<<<dim3(32), dim3(256), 0, stream>>>(particles, lw, sp, A, B, muP, spT, av1);
  // pass 1: tile = mu chunks (j, eav1), stationary = sp' (i) -> S1 partials per i
  k_pass<<<dim3(64, 16), dim3(256), 0, stream>>>(muP, spT, av1, nullptr, p1);
  // pass 2: tile = sp' chunks (i, eav2 in prologue), stationary = mu (j)
  k_pass<<<dim3(64, 16), dim3(256), 0, stream>>>(spT, muP, w, p1, p2);
  k_out<<<dim3(32), dim3(256), 0, stream>>>(p2, av1, out);
}

// Round 12
// 46.430 us; speedup vs baseline: 11.2793x; 1.3593x over previous
//
#include <hip/hip_runtime.h>

#define LOG2E 1.44269504088896340736f
#define LN2   0.69314718055994530942f

typedef __attribute__((ext_vector_type(8))) short bf16x8;
typedef __attribute__((ext_vector_type(4))) float f32x4;
typedef __attribute__((ext_vector_type(16))) float f32x16;

// ws float offsets
#define WS_MUP  0        // 8192 x 16 u32 : packed [mu_hi|mu_lo] bf16
#define WS_SPT  131072   // 8192 x 16 u32 : packed [sp'_hi|sp'_lo], sp' = log2e*sp
#define WS_AV1  262144   // 8192 f32
#define WS_P1   270336   // 64 x 8192 f32 partials, pass 1
#define WS_P2   794624   // 64 x 8192 f32 partials, pass 2

__device__ __forceinline__ unsigned short bf16_rne(float x) {
  unsigned int u = __float_as_uint(x);
  u = u + 0x7FFFu + ((u >> 16) & 1u);
  return (unsigned short)(u >> 16);
}
__device__ __forceinline__ float bf16f(unsigned short h) {
  return __uint_as_float(((unsigned int)h) << 16);
}
__device__ __forceinline__ float fast_exp2(float x) {
#if __has_builtin(__builtin_amdgcn_exp2f)
  return __builtin_amdgcn_exp2f(x);
#else
  return exp2f(x);
#endif
}
__device__ __forceinline__ float fast_log2(float x) {
#if __has_builtin(__builtin_amdgcn_logf)
  return __builtin_amdgcn_logf(x);
#else
  return log2f(x);
#endif
}

__device__ __forceinline__ void pack_row(const float* v, unsigned int* buf) {
#pragma unroll
  for (int k = 0; k < 16; k += 2) {
    unsigned short h0 = bf16_rne(v[k]);
    unsigned short h1 = bf16_rne(v[k + 1]);
    float l0 = v[k] - bf16f(h0);
    float l1 = v[k + 1] - bf16f(h1);
    buf[k >> 1] = (unsigned int)h0 | ((unsigned int)h1 << 16);
    buf[8 + (k >> 1)] = (unsigned int)bf16_rne(l0) | ((unsigned int)bf16_rne(l1) << 16);
  }
}

__global__ __launch_bounds__(256) void k_prep(
    const float* __restrict__ particles, const float* __restrict__ lw,
    const float* __restrict__ sp,
    const float* __restrict__ A, const float* __restrict__ B,
    unsigned int* __restrict__ muP, unsigned int* __restrict__ spT,
    float* __restrict__ av1) {
  int j = blockIdx.x * 256 + threadIdx.x;
  float x[24];
  {
    const float4* p4 = (const float4*)(particles + (size_t)j * 24);
#pragma unroll
    for (int q = 0; q < 6; ++q) {
      float4 v = p4[q];
      x[q * 4 + 0] = v.x; x[q * 4 + 1] = v.y; x[q * 4 + 2] = v.z; x[q * 4 + 3] = v.w;
    }
  }
  float mrow[16];
  float m2 = 0.f;
#pragma unroll
  for (int k = 0; k < 16; ++k) {
    float s = 0.f;
#pragma unroll
    for (int l = 0; l < 16; ++l) s += x[l] * A[k * 16 + l];
#pragma unroll
    for (int l = 0; l < 8; ++l) s += x[16 + l] * B[k * 8 + l];
    mrow[k] = s;
    m2 += s * s;
  }
  av1[j] = LOG2E * (lw[j] - 0.5f * m2);

  unsigned int buf[16];
  pack_row(mrow, buf);
  {
    uint4* dst = (uint4*)(muP + (size_t)j * 16);
#pragma unroll
    for (int q = 0; q < 4; ++q)
      dst[q] = make_uint4(buf[q * 4], buf[q * 4 + 1], buf[q * 4 + 2], buf[q * 4 + 3]);
  }
  float srow[16];
  {
    const float4* s4 = (const float4*)(sp + (size_t)j * 16);
#pragma unroll
    for (int q = 0; q < 4; ++q) {
      float4 v = s4[q];
      srow[q * 4 + 0] = LOG2E * v.x; srow[q * 4 + 1] = LOG2E * v.y;
      srow[q * 4 + 2] = LOG2E * v.z; srow[q * 4 + 3] = LOG2E * v.w;
    }
  }
  pack_row(srow, buf);
  {
    uint4* dst = (uint4*)(spT + (size_t)j * 16);
#pragma unroll
    for (int q = 0; q < 4; ++q)
      dst[q] = make_uint4(buf[q * 4], buf[q * 4 + 1], buf[q * 4 + 2], buf[q * 4 + 3]);
  }
}

#define EXPSUM16(d, acc)                                              \
  {                                                                   \
    float e0 = fast_exp2(d[0])  + fast_exp2(d[1]);                    \
    float e1 = fast_exp2(d[2])  + fast_exp2(d[3]);                    \
    float e2 = fast_exp2(d[4])  + fast_exp2(d[5]);                    \
    float e3 = fast_exp2(d[6])  + fast_exp2(d[7]);                    \
    float e4 = fast_exp2(d[8])  + fast_exp2(d[9]);                    \
    float e5 = fast_exp2(d[10]) + fast_exp2(d[11]);                   \
    float e6 = fast_exp2(d[12]) + fast_exp2(d[13]);                   \
    float e7 = fast_exp2(d[14]) + fast_exp2(d[15]);                   \
    acc += ((e0 + e1) + (e2 + e3)) + ((e4 + e5) + (e6 + e7));         \
  }

#define MFMA3(dd, ah, al, bh, bl, C)                                            \
  f32x16 dd = __builtin_amdgcn_mfma_f32_32x32x16_bf16(ah, bh, C, 0, 0, 0);      \
  dd = __builtin_amdgcn_mfma_f32_32x32x16_bf16(al, bh, dd, 0, 0, 0);            \
  dd = __builtin_amdgcn_mfma_f32_32x32x16_bf16(ah, bl, dd, 0, 0, 0);

// part[chunk][r] = sum over 128 tile rows t of chunk of 2^( av[t] + stat_r . tile_t )
// 32x32x16 MFMA, 3-MFMA hi/lo split, FOUR stationary strips per wave (128 rows):
// per-tile shared costs (2 a-reads + 4 C-init reads + C build) amortize over
// 4096 pairs. Strip-pairs processed sequentially to cap live d-frags at 2
// (VGPR audit ~107 < 128 @ launch_bounds(256,4) — round-11 spill lesson).
__global__ __launch_bounds__(256, 4) void k_pass(
    const unsigned int* __restrict__ tilev,
    const unsigned int* __restrict__ statv,
    const float* __restrict__ avv,
    const float* __restrict__ psrc,
    float* __restrict__ part) {
  __shared__ __align__(16) unsigned int tl[128 * 20];
  __shared__ __align__(16) float av_l[128];
  __shared__ float sums[256];
  const int t = threadIdx.x;
  const int chunk = blockIdx.x;  // 0..63, fast
  const int sg    = blockIdx.y;  // 0..15

  // stage tile: 128 rows x 16 u32 -> LDS stride 20 (balanced b128 slots)
  {
    const uint4* src = (const uint4*)(tilev + (size_t)chunk * 2048);
#pragma unroll
    for (int q = 0; q < 2; ++q) {
      int f = t + 256 * q;
      int row = f >> 2, s = f & 3;
      *(uint4*)(tl + row * 20 + s * 4) = src[f];
    }
  }

  if (psrc == nullptr) {
    if (t < 128) av_l[t] = avv[chunk * 128 + t];
  } else {
    const int row = t & 127, half = t >> 7;
    float s = 0.f;
    const float* p = psrc + (size_t)(half * 32) * 8192 + chunk * 128 + row;
#pragma unroll 8
    for (int c = 0; c < 32; ++c) s += p[(size_t)c * 8192];
    sums[t] = s;
    __syncthreads();
    if (t < 128) {
      float sv = sums[t] + sums[t + 128];
      av_l[t] = LOG2E * avv[chunk * 128 + t] - fast_log2(sv);
    }
  }
  __syncthreads();

  const int l = t & 63;
  const int wave = t >> 6;
  const int lr = l & 31;   // A-row / B-col / D-col selector
  const int hi = l >> 5;   // k-half selector
  const int r0 = sg * 512 + wave * 128;  // wave's 128 stationary rows

  // stationary B fragments, strips 0..3
  const unsigned int* brow0 = statv + (size_t)(r0 + lr) * 16 + hi * 4;
  const unsigned int* brow1 = statv + (size_t)(r0 + 32 + lr) * 16 + hi * 4;
  const unsigned int* brow2 = statv + (size_t)(r0 + 64 + lr) * 16 + hi * 4;
  const unsigned int* brow3 = statv + (size_t)(r0 + 96 + lr) * 16 + hi * 4;
  const bf16x8 b_hi0 = *(const bf16x8*)brow0;
  const bf16x8 b_lo0 = *(const bf16x8*)(brow0 + 8);
  const bf16x8 b_hi1 = *(const bf16x8*)brow1;
  const bf16x8 b_lo1 = *(const bf16x8*)(brow1 + 8);
  const bf16x8 b_hi2 = *(const bf16x8*)brow2;
  const bf16x8 b_lo2 = *(const bf16x8*)(brow2 + 8);
  const bf16x8 b_hi3 = *(const bf16x8*)brow3;
  const bf16x8 b_lo3 = *(const bf16x8*)(brow3 + 8);

  float acc0 = 0.f, acc1 = 0.f, acc2 = 0.f, acc3 = 0.f;
#pragma unroll
  for (int tile = 0; tile < 4; ++tile) {
    const unsigned int* arow = tl + (tile * 32 + lr) * 20 + hi * 4;
    const bf16x8 a_hi = *(const bf16x8*)arow;
    const bf16x8 a_lo = *(const bf16x8*)(arow + 8);

    // C init = av[tile row]; C row = (reg&3) + 8*(reg>>2) + 4*hi  (shared by all strips)
    const f32x4 c0 = *(const f32x4*)(av_l + tile * 32 + 0  + 4 * hi);
    const f32x4 c1 = *(const f32x4*)(av_l + tile * 32 + 8  + 4 * hi);
    const f32x4 c2 = *(const f32x4*)(av_l + tile * 32 + 16 + 4 * hi);
    const f32x4 c3 = *(const f32x4*)(av_l + tile * 32 + 24 + 4 * hi);
    f32x16 C;
#pragma unroll
    for (int e = 0; e < 4; ++e) {
      C[e] = c0[e]; C[4 + e] = c1[e]; C[8 + e] = c2[e]; C[12 + e] = c3[e];
    }

    {  // strip pair 0/1
      MFMA3(d0, a_hi, a_lo, b_hi0, b_lo0, C)
      MFMA3(d1, a_hi, a_lo, b_hi1, b_lo1, C)
      EXPSUM16(d0, acc0)
      EXPSUM16(d1, acc1)
    }
    {  // strip pair 2/3 (d-frag registers reusable after the exp-sums above)
      MFMA3(d2, a_hi, a_lo, b_hi2, b_lo2, C)
      MFMA3(d3, a_hi, a_lo, b_hi3, b_lo3, C)
      EXPSUM16(d2, acc2)
      EXPSUM16(d3, acc3)
    }
  }
  acc0 += __shfl_xor(acc0, 32);
  acc1 += __shfl_xor(acc1, 32);
  acc2 += __shfl_xor(acc2, 32);
  acc3 += __shfl_xor(acc3, 32);
  float* base = part + (size_t)chunk * 8192 + r0 + lr;
  if (l < 32) { base[0]  = acc0; base[64] = acc2; }
  else        { base[32] = acc1; base[96] = acc3; }
}

__global__ __launch_bounds__(256) void k_out(
    const float* __restrict__ part, const float* __restrict__ av1,
    float* __restrict__ out) {
  int j = blockIdx.x * 256 + threadIdx.x;
  float s = 0.f;
#pragma unroll
  for (int c = 0; c < 64; ++c) s += part[(size_t)c * 8192 + j];
  out[j] = LN2 * (av1[j] + fast_log2(s));
}

extern "C" void kernel_launch(void* const* d_in, const int* in_sizes, int n_in,
                              void* d_out, int out_size, void* d_ws, size_t ws_size,
                              hipStream_t stream) {
  const float* particles = (const float*)d_in[0];
  const float* lw        = (const float*)d_in[1];
  const float* sp        = (const float*)d_in[2];
  const float* w         = (const float*)d_in[3];
  const float* A         = (const float*)d_in[4];
  const float* B         = (const float*)d_in[5];

  float* ws = (float*)d_ws;
  unsigned int* muP = (unsigned int*)(ws + WS_MUP);
  unsigned int* spT = (unsigned int*)(ws + WS_SPT);
  float* av1  = ws + WS_AV1;
  float* p1   = ws + WS_P1;
  float* p2   = ws + WS_P2;
  float* out  = (float*)d_out;

  k_prep<<<dim3(32), dim3(256), 0, stream>>>(particles, lw, sp, A, B, muP, spT, av1);
  // pass 1: tile = mu chunks (j, av1), stationary = sp' (i) -> S1 partials per i
  k_pass<<<dim3(64, 16), dim3(256), 0, stream>>>(muP, spT, av1, nullptr, p1);
  // pass 2: tile = sp' chunks (i, av2 in prologue), stationary = mu (j)
  k_pass<<<dim3(64, 16), dim3(256), 0, stream>>>(spT, muP, w, p1, p2);
  k_out<<<dim3(32), dim3(256), 0, stream>>>(p2, av1, out);
}